// Round 14
// baseline (28.579 us; speedup 1.0000x reference)
//
#include <hip/hip_runtime.h>
#include <cmath>

#define NCLS 80

// cells per level: 32*3*g*g for g in {52,26,13}
#define CELL0 259584
#define CELL1 64896
#define CELL2 16224
#define CELLT (CELL0 + CELL1 + CELL2)   // 340704

#define TGT_BLOCKS 720                  // blocks running the targets phase (32 entries each)
#define NBLK 1331                       // total blocks: 1331*256 = 340736 >= CELLT

// ws layout (floats), no zero-init needed (all read slots written unconditionally):
//  [TPART .. +TGT_BLOCKS*4)  per-block {lbox, cls, cnt, xt}   (lev = bid/240)
//  [OPART .. +NBLK*4)        per-block {sp0, sp1, sp2, pad}
#define TPART 0
#define OPART (TGT_BLOCKS * 4)

__device__ __constant__ float c_anch[3][3][2] = {
    {{1.25f, 1.625f}, {2.0f, 3.75f}, {4.125f, 2.875f}},
    {{1.875f, 3.8125f}, {3.875f, 2.8125f}, {3.6875f, 7.4375f}},
    {{3.625f, 2.8125f}, {4.875f, 6.1875f}, {11.65625f, 10.1875f}}};
__device__ __constant__ float c_offx[5] = {0.f, 0.5f, 0.f, -0.5f, 0.f};
__device__ __constant__ float c_offy[5] = {0.f, 0.f, 0.5f, 0.f, -0.5f};

__device__ __forceinline__ float bce(float x, float y) {
    return fmaxf(x, 0.f) - x * y + log1pf(expf(-fabsf(x)));
}
__device__ __forceinline__ float softplus_bce0(float x) {  // bce(x, 0)
    return fmaxf(x, 0.f) + log1pf(expf(-fabsf(x)));
}

// ONE compute kernel, no atomics, no barrier, no tobj (proven R11/R13 structure):
//  * blocks 0..719: 8-lane-group targets phase -> {lbox, cls, cnt, xt} partials,
//    xt = sum(x_obj * score) replaces scatter-max/tobj (bce(x,t) = softplus(x) - x*t).
//  * ALL blocks: one strided softplus(x_obj) element (i = bid*256 + tid).
__global__ __launch_bounds__(256) void k_all(const float* __restrict__ p0,
                                             const float* __restrict__ p1,
                                             const float* __restrict__ p2,
                                             const float* __restrict__ tgt,
                                             float* __restrict__ ws) {
    const int bid = blockIdx.x;
    const int lane = threadIdx.x & 63;
    const int wid = threadIdx.x >> 6;

    // ---- obj phase: issue the strided load FIRST (hides under targets compute) ----
    const int i = bid * 256 + threadIdx.x;
    float xo = 0.f;
    const bool have = (i < CELLT);
    if (have) {
        if (i < CELL0) xo = p0[(long)i * 85 + 4];
        else if (i < CELL0 + CELL1) xo = p1[(long)(i - CELL0) * 85 + 4];
        else xo = p2[(long)(i - (CELL0 + CELL1)) * 85 + 4];
    }

    // ---- targets phase (blocks 0..719) ----
    if (bid < TGT_BLOCKS) {
        const int g = lane & 7;
        const int grp = lane >> 3;
        const int gid = bid * 32 + wid * 8 + grp;  // entry 0..23039

        const int lev = gid / 7680;
        const int m = gid - lev * 7680;
        const int o = m / 1536;
        const int n = m - o * 1536;
        const int a = n >> 9;
        const int j = n & 511;

        const int gsz = (lev == 0) ? 52 : ((lev == 1) ? 26 : 13);
        const float* p = (lev == 0) ? p0 : ((lev == 1) ? p1 : p2);

        const float2 t01 = *(const float2*)(tgt + j * 6 + 0);
        const float2 t23 = *(const float2*)(tgt + j * 6 + 2);
        const float2 t45 = *(const float2*)(tgt + j * 6 + 4);
        const float img = t01.x, cls = t01.y;
        const float x1 = t23.x, y1 = t23.y, x2 = t45.x, y2 = t45.y;
        const float w = (float)gsz, h = (float)gsz;
        const float cx = (x1 + x2) * 0.5f, cy = (y1 + y2) * 0.5f;
        const float tw = x2 - x1, th = y2 - y1;
        const float gx = cx * w, gy = cy * h, gw = tw * w, gh = th * h;

        const float ax = c_anch[lev][a][0], ay = c_anch[lev][a][1];
        const float rx = gw / ax, ry = gh / ay;
        const float mr = fmaxf(fmaxf(rx, 1.0f / rx), fmaxf(ry, 1.0f / ry));
        bool valid = (mr < 4.0f);
        if (o == 1)
            valid = valid && (gx - floorf(gx) < 0.5f) && (gx > 1.0f);
        else if (o == 2)
            valid = valid && (gy - floorf(gy) < 0.5f) && (gy > 1.0f);
        else if (o == 3) {
            const float gxi = w - gx;
            valid = valid && (gxi - floorf(gxi) < 0.5f) && (gxi > 1.0f);
        } else if (o == 4) {
            const float gyi = h - gy;
            valid = valid && (gyi - floorf(gyi) < 0.5f) && (gyi > 1.0f);
        }

        float lbox_c = 0.f, cls_c = 0.f, cnt_c = 0.f, xt_c = 0.f;

        if (valid) {
            const float gijx = floorf(gx - c_offx[o]);
            const float gijy = floorf(gy - c_offy[o]);
            int gi = (int)gijx;
            gi = min(max(gi, 0), gsz - 1);
            int gj = (int)gijy;
            gj = min(max(gj, 0), gsz - 1);
            const int b = (int)img;
            const int c = (int)cls;
            const int cell = ((b * 3 + a) * gsz + gj) * gsz + gi;
            const long base = (long)cell * 85;

            float x0 = 0.f, s = 0.f;
#pragma unroll
            for (int k = 0; k < 11; ++k) {
                const int elem = g + 8 * k;
                if (elem < 85) {
                    const float x = p[base + elem];
                    if (k == 0) x0 = x;
                    if (elem >= 5) s += bce(x, (elem - 5 == c) ? 0.95f : 0.05f);
                }
            }
            cls_c = s;

            const int gb = lane & 56;
            const float t0 = __shfl(x0, gb + 0);
            const float t1 = __shfl(x0, gb + 1);
            const float t2 = __shfl(x0, gb + 2);
            const float t3 = __shfl(x0, gb + 3);
            const float x4 = __shfl(x0, gb + 4);  // obj logit of this cell

            const float sx = 1.f / (1.f + expf(-t0));
            const float sy = 1.f / (1.f + expf(-t1));
            const float sw = 1.f / (1.f + expf(-t2));
            const float shh = 1.f / (1.f + expf(-t3));
            const float pxc = sx * 2.f - 0.5f;
            const float pyc = sy * 2.f - 0.5f;
            const float pw = (sw * 2.f) * (sw * 2.f) * ax;
            const float ph = (shh * 2.f) * (shh * 2.f) * ay;

            const float tbx = gx - gijx, tby = gy - gijy, tbw = gw, tbh = gh;

            const float b1x1 = pxc - pw * 0.5f, b1x2 = pxc + pw * 0.5f;
            const float b1y1 = pyc - ph * 0.5f, b1y2 = pyc + ph * 0.5f;
            const float b2x1 = tbx - tbw * 0.5f, b2x2 = tbx + tbw * 0.5f;
            const float b2y1 = tby - tbh * 0.5f, b2y2 = tby + tbh * 0.5f;
            float iw = fminf(b1x2, b2x2) - fmaxf(b1x1, b2x1);
            iw = fmaxf(iw, 0.f);
            float ih = fminf(b1y2, b2y2) - fmaxf(b1y1, b2y1);
            ih = fmaxf(ih, 0.f);
            const float inter = iw * ih;
            const float uni = pw * ph + tbw * tbh - inter + 1e-7f;
            const float iou = inter / uni;
            const float cw = fmaxf(b1x2, b2x2) - fminf(b1x1, b2x1);
            const float ch = fmaxf(b1y2, b2y2) - fminf(b1y1, b2y1);
            const float c2 = cw * cw + ch * ch + 1e-7f;
            const float dx = b2x1 + b2x2 - b1x1 - b1x2;
            const float dy = b2y1 + b2y2 - b1y1 - b1y2;
            const float rho2 = (dx * dx + dy * dy) * 0.25f;
            const float dv = atanf(tbw / tbh) - atanf(pw / ph);
            const float v = 0.40528473f * dv * dv;  // 4/pi^2
            const float alpha = v / (v - iou + 1.0000001f);
            const float ciou = iou - (rho2 / c2 + v * alpha);

            if (g == 0) {
                lbox_c = 1.f - ciou;
                cnt_c = 1.f;
                const float score = fmaxf(ciou, 0.f);
                xt_c = x4 * score;
            }
        }

#pragma unroll
        for (int msk = 1; msk < 64; msk <<= 1) {
            lbox_c += __shfl_xor(lbox_c, msk);
            cls_c += __shfl_xor(cls_c, msk);
            cnt_c += __shfl_xor(cnt_c, msk);
            xt_c += __shfl_xor(xt_c, msk);
        }
        __shared__ float st[4][4];
        if (lane == 0) {
            st[wid][0] = lbox_c; st[wid][1] = cls_c;
            st[wid][2] = cnt_c;  st[wid][3] = xt_c;
        }
        __syncthreads();
        if (threadIdx.x == 0) {
            float* slot = ws + TPART + bid * 4;
#pragma unroll
            for (int q = 0; q < 4; ++q)
                slot[q] = st[0][q] + st[1][q] + st[2][q] + st[3][q];
        }
    }

    // ---- obj softplus partials (all blocks) ----
    float v0 = 0.f, v1 = 0.f, v2 = 0.f;
    if (have) {
        const float sp = softplus_bce0(xo);
        if (i < CELL0) v0 = sp;
        else if (i < CELL0 + CELL1) v1 = sp;
        else v2 = sp;
    }
#pragma unroll
    for (int msk = 1; msk < 64; msk <<= 1) {
        v0 += __shfl_xor(v0, msk);
        v1 += __shfl_xor(v1, msk);
        v2 += __shfl_xor(v2, msk);
    }
    __shared__ float so[4][3];
    if (lane == 0) { so[wid][0] = v0; so[wid][1] = v1; so[wid][2] = v2; }
    __syncthreads();
    if (threadIdx.x == 0) {
        float* slot = ws + OPART + bid * 4;
        slot[0] = so[0][0] + so[1][0] + so[2][0] + so[3][0];
        slot[1] = so[0][1] + so[1][1] + so[2][1] + so[3][1];
        slot[2] = so[0][2] + so[1][2] + so[2][2] + so[3][2];
        slot[3] = 0.f;
    }
}

// 1024-thread single-block reducer, fully static named accumulators (rule #20).
// TPART: one conditional float4/thread (720 slots across 3 static level ranges).
// OPART: 2 strided float4 iterations (1331 slots / 1024 threads).
__global__ __launch_bounds__(1024) void k_final(const float* __restrict__ ws,
                                                float* __restrict__ out) {
    const int tid = threadIdx.x;
    const int wid = tid >> 6, lane = tid & 63;

    float lb0 = 0.f, cl0 = 0.f, cn0 = 0.f, xt0 = 0.f;
    float lb1 = 0.f, cl1 = 0.f, cn1 = 0.f, xt1 = 0.f;
    float lb2 = 0.f, cl2 = 0.f, cn2 = 0.f, xt2 = 0.f;
    float sp0 = 0.f, sp1 = 0.f, sp2 = 0.f;

    if (tid < 240) {
        const float4 s = *(const float4*)(ws + TPART + tid * 4);
        lb0 = s.x; cl0 = s.y; cn0 = s.z; xt0 = s.w;
    } else if (tid < 480) {
        const float4 s = *(const float4*)(ws + TPART + tid * 4);
        lb1 = s.x; cl1 = s.y; cn1 = s.z; xt1 = s.w;
    } else if (tid < 720) {
        const float4 s = *(const float4*)(ws + TPART + tid * 4);
        lb2 = s.x; cl2 = s.y; cn2 = s.z; xt2 = s.w;
    }
    {
        const float4 s = *(const float4*)(ws + OPART + tid * 4);  // tid < 1331 always
        sp0 = s.x; sp1 = s.y; sp2 = s.z;
    }
    if (tid + 1024 < NBLK) {
        const float4 s = *(const float4*)(ws + OPART + (tid + 1024) * 4);
        sp0 += s.x; sp1 += s.y; sp2 += s.z;
    }

#pragma unroll
    for (int msk = 1; msk < 64; msk <<= 1) {
        lb0 += __shfl_xor(lb0, msk); cl0 += __shfl_xor(cl0, msk);
        cn0 += __shfl_xor(cn0, msk); xt0 += __shfl_xor(xt0, msk);
        lb1 += __shfl_xor(lb1, msk); cl1 += __shfl_xor(cl1, msk);
        cn1 += __shfl_xor(cn1, msk); xt1 += __shfl_xor(xt1, msk);
        lb2 += __shfl_xor(lb2, msk); cl2 += __shfl_xor(cl2, msk);
        cn2 += __shfl_xor(cn2, msk); xt2 += __shfl_xor(xt2, msk);
        sp0 += __shfl_xor(sp0, msk); sp1 += __shfl_xor(sp1, msk);
        sp2 += __shfl_xor(sp2, msk);
    }

    __shared__ float sf[16][15];
    if (lane == 0) {
        sf[wid][0] = lb0;  sf[wid][1] = lb1;  sf[wid][2] = lb2;
        sf[wid][3] = cl0;  sf[wid][4] = cl1;  sf[wid][5] = cl2;
        sf[wid][6] = cn0;  sf[wid][7] = cn1;  sf[wid][8] = cn2;
        sf[wid][9] = xt0;  sf[wid][10] = xt1; sf[wid][11] = xt2;
        sf[wid][12] = sp0; sf[wid][13] = sp1; sf[wid][14] = sp2;
    }
    __syncthreads();

    if (tid == 0) {
        float t[15];
#pragma unroll
        for (int q = 0; q < 15; ++q) {
            float s = 0.f;
#pragma unroll
            for (int wv = 0; wv < 16; ++wv) s += sf[wv][q];
            t[q] = s;
        }
        float lbox = 0.f, lobj = 0.f, lcls = 0.f;
        const float bal[3] = {4.0f, 1.0f, 0.4f};
        const float ncell[3] = {(float)CELL0, (float)CELL1, (float)CELL2};
#pragma unroll
        for (int l = 0; l < 3; ++l) {
            const float nv = fmaxf(t[6 + l], 1.0f);
            lbox += t[l] / nv;
            lcls += t[3 + l] / (nv * (float)NCLS);
            lobj += (t[12 + l] - t[9 + l]) / ncell[l] * bal[l];  // softplus - x*t
        }
        lbox *= 0.05f;
        lcls *= 0.5f;
        const float total = (lbox + lobj + lcls) * 32.0f;
        out[0] = total;
        out[1] = lbox;
        out[2] = lobj;
        out[3] = lcls;
    }
}

extern "C" void kernel_launch(void* const* d_in, const int* in_sizes, int n_in,
                              void* d_out, int out_size, void* d_ws, size_t ws_size,
                              hipStream_t stream) {
    const float* p0 = (const float*)d_in[0];
    const float* p1 = (const float*)d_in[1];
    const float* p2 = (const float*)d_in[2];
    const float* tgt = (const float*)d_in[3];
    float* ws = (float*)d_ws;
    float* out = (float*)d_out;

    k_all<<<NBLK, 256, 0, stream>>>(p0, p1, p2, tgt, ws);
    k_final<<<1, 1024, 0, stream>>>(ws, out);
}

// Round 15
// 26.145 us; speedup vs baseline: 1.0931x; 1.0931x over previous
//
#include <hip/hip_runtime.h>
#include <cmath>

#define NCLS 80

// cells per level: 32*3*g*g for g in {52,26,13}
#define CELL0 259584
#define CELL1 64896
#define CELL2 16224
#define CELLT (CELL0 + CELL1 + CELL2)   // 340704

#define TGT_BLOCKS 720                  // blocks running the targets phase (32 entries each)
#define NBLK 1331                       // total blocks: 1331*256 = 340736 >= CELLT

// ws layout (floats), no zero-init needed (all read slots written unconditionally):
//  [TPART .. +TGT_BLOCKS*4)  per-block {lbox, cls, cnt, xt}   (lev = bid/240)
//  [OPART .. +NBLK*4)        per-block {sp0, sp1, sp2, pad}
#define TPART 0
#define OPART (TGT_BLOCKS * 4)

__device__ __constant__ float c_anch[3][3][2] = {
    {{1.25f, 1.625f}, {2.0f, 3.75f}, {4.125f, 2.875f}},
    {{1.875f, 3.8125f}, {3.875f, 2.8125f}, {3.6875f, 7.4375f}},
    {{3.625f, 2.8125f}, {4.875f, 6.1875f}, {11.65625f, 10.1875f}}};
__device__ __constant__ float c_offx[5] = {0.f, 0.5f, 0.f, -0.5f, 0.f};
__device__ __constant__ float c_offy[5] = {0.f, 0.f, 0.5f, 0.f, -0.5f};

__device__ __forceinline__ float bce(float x, float y) {
    return fmaxf(x, 0.f) - x * y + log1pf(expf(-fabsf(x)));
}
__device__ __forceinline__ float softplus_bce0(float x) {  // bce(x, 0)
    return fmaxf(x, 0.f) + log1pf(expf(-fabsf(x)));
}

// ONE compute kernel, no atomics, no barrier, no tobj (best-measured R13 structure):
//  * blocks 0..719: 8-lane-group targets phase -> {lbox, cls, cnt, xt} partials,
//    xt = sum(x_obj * score) replaces scatter-max/tobj (bce(x,t) = softplus(x) - x*t).
//  * ALL blocks: one strided softplus(x_obj) element (i = bid*256 + tid).
__global__ __launch_bounds__(256) void k_all(const float* __restrict__ p0,
                                             const float* __restrict__ p1,
                                             const float* __restrict__ p2,
                                             const float* __restrict__ tgt,
                                             float* __restrict__ ws) {
    const int bid = blockIdx.x;
    const int lane = threadIdx.x & 63;
    const int wid = threadIdx.x >> 6;

    // ---- obj phase: issue the strided load FIRST (hides under targets compute) ----
    const int i = bid * 256 + threadIdx.x;
    float xo = 0.f;
    const bool have = (i < CELLT);
    if (have) {
        if (i < CELL0) xo = p0[(long)i * 85 + 4];
        else if (i < CELL0 + CELL1) xo = p1[(long)(i - CELL0) * 85 + 4];
        else xo = p2[(long)(i - (CELL0 + CELL1)) * 85 + 4];
    }

    // ---- targets phase (blocks 0..719) ----
    if (bid < TGT_BLOCKS) {
        const int g = lane & 7;
        const int grp = lane >> 3;
        const int gid = bid * 32 + wid * 8 + grp;  // entry 0..23039

        const int lev = gid / 7680;
        const int m = gid - lev * 7680;
        const int o = m / 1536;
        const int n = m - o * 1536;
        const int a = n >> 9;
        const int j = n & 511;

        const int gsz = (lev == 0) ? 52 : ((lev == 1) ? 26 : 13);
        const float* p = (lev == 0) ? p0 : ((lev == 1) ? p1 : p2);

        const float2 t01 = *(const float2*)(tgt + j * 6 + 0);
        const float2 t23 = *(const float2*)(tgt + j * 6 + 2);
        const float2 t45 = *(const float2*)(tgt + j * 6 + 4);
        const float img = t01.x, cls = t01.y;
        const float x1 = t23.x, y1 = t23.y, x2 = t45.x, y2 = t45.y;
        const float w = (float)gsz, h = (float)gsz;
        const float cx = (x1 + x2) * 0.5f, cy = (y1 + y2) * 0.5f;
        const float tw = x2 - x1, th = y2 - y1;
        const float gx = cx * w, gy = cy * h, gw = tw * w, gh = th * h;

        const float ax = c_anch[lev][a][0], ay = c_anch[lev][a][1];
        const float rx = gw / ax, ry = gh / ay;
        const float mr = fmaxf(fmaxf(rx, 1.0f / rx), fmaxf(ry, 1.0f / ry));
        bool valid = (mr < 4.0f);
        if (o == 1)
            valid = valid && (gx - floorf(gx) < 0.5f) && (gx > 1.0f);
        else if (o == 2)
            valid = valid && (gy - floorf(gy) < 0.5f) && (gy > 1.0f);
        else if (o == 3) {
            const float gxi = w - gx;
            valid = valid && (gxi - floorf(gxi) < 0.5f) && (gxi > 1.0f);
        } else if (o == 4) {
            const float gyi = h - gy;
            valid = valid && (gyi - floorf(gyi) < 0.5f) && (gyi > 1.0f);
        }

        float lbox_c = 0.f, cls_c = 0.f, cnt_c = 0.f, xt_c = 0.f;

        if (valid) {
            const float gijx = floorf(gx - c_offx[o]);
            const float gijy = floorf(gy - c_offy[o]);
            int gi = (int)gijx;
            gi = min(max(gi, 0), gsz - 1);
            int gj = (int)gijy;
            gj = min(max(gj, 0), gsz - 1);
            const int b = (int)img;
            const int c = (int)cls;
            const int cell = ((b * 3 + a) * gsz + gj) * gsz + gi;
            const long base = (long)cell * 85;

            float x0 = 0.f, s = 0.f;
#pragma unroll
            for (int k = 0; k < 11; ++k) {
                const int elem = g + 8 * k;
                if (elem < 85) {
                    const float x = p[base + elem];
                    if (k == 0) x0 = x;
                    if (elem >= 5) s += bce(x, (elem - 5 == c) ? 0.95f : 0.05f);
                }
            }
            cls_c = s;

            const int gb = lane & 56;
            const float t0 = __shfl(x0, gb + 0);
            const float t1 = __shfl(x0, gb + 1);
            const float t2 = __shfl(x0, gb + 2);
            const float t3 = __shfl(x0, gb + 3);
            const float x4 = __shfl(x0, gb + 4);  // obj logit of this cell

            const float sx = 1.f / (1.f + expf(-t0));
            const float sy = 1.f / (1.f + expf(-t1));
            const float sw = 1.f / (1.f + expf(-t2));
            const float shh = 1.f / (1.f + expf(-t3));
            const float pxc = sx * 2.f - 0.5f;
            const float pyc = sy * 2.f - 0.5f;
            const float pw = (sw * 2.f) * (sw * 2.f) * ax;
            const float ph = (shh * 2.f) * (shh * 2.f) * ay;

            const float tbx = gx - gijx, tby = gy - gijy, tbw = gw, tbh = gh;

            const float b1x1 = pxc - pw * 0.5f, b1x2 = pxc + pw * 0.5f;
            const float b1y1 = pyc - ph * 0.5f, b1y2 = pyc + ph * 0.5f;
            const float b2x1 = tbx - tbw * 0.5f, b2x2 = tbx + tbw * 0.5f;
            const float b2y1 = tby - tbh * 0.5f, b2y2 = tby + tbh * 0.5f;
            float iw = fminf(b1x2, b2x2) - fmaxf(b1x1, b2x1);
            iw = fmaxf(iw, 0.f);
            float ih = fminf(b1y2, b2y2) - fmaxf(b1y1, b2y1);
            ih = fmaxf(ih, 0.f);
            const float inter = iw * ih;
            const float uni = pw * ph + tbw * tbh - inter + 1e-7f;
            const float iou = inter / uni;
            const float cw = fmaxf(b1x2, b2x2) - fminf(b1x1, b2x1);
            const float ch = fmaxf(b1y2, b2y2) - fminf(b1y1, b2y1);
            const float c2 = cw * cw + ch * ch + 1e-7f;
            const float dx = b2x1 + b2x2 - b1x1 - b1x2;
            const float dy = b2y1 + b2y2 - b1y1 - b1y2;
            const float rho2 = (dx * dx + dy * dy) * 0.25f;
            const float dv = atanf(tbw / tbh) - atanf(pw / ph);
            const float v = 0.40528473f * dv * dv;  // 4/pi^2
            const float alpha = v / (v - iou + 1.0000001f);
            const float ciou = iou - (rho2 / c2 + v * alpha);

            if (g == 0) {
                lbox_c = 1.f - ciou;
                cnt_c = 1.f;
                const float score = fmaxf(ciou, 0.f);
                xt_c = x4 * score;
            }
        }

#pragma unroll
        for (int msk = 1; msk < 64; msk <<= 1) {
            lbox_c += __shfl_xor(lbox_c, msk);
            cls_c += __shfl_xor(cls_c, msk);
            cnt_c += __shfl_xor(cnt_c, msk);
            xt_c += __shfl_xor(xt_c, msk);
        }
        __shared__ float st[4][4];
        if (lane == 0) {
            st[wid][0] = lbox_c; st[wid][1] = cls_c;
            st[wid][2] = cnt_c;  st[wid][3] = xt_c;
        }
        __syncthreads();
        if (threadIdx.x == 0) {
            float* slot = ws + TPART + bid * 4;
#pragma unroll
            for (int q = 0; q < 4; ++q)
                slot[q] = st[0][q] + st[1][q] + st[2][q] + st[3][q];
        }
    }

    // ---- obj softplus partials (all blocks) ----
    float v0 = 0.f, v1 = 0.f, v2 = 0.f;
    if (have) {
        const float sp = softplus_bce0(xo);
        if (i < CELL0) v0 = sp;
        else if (i < CELL0 + CELL1) v1 = sp;
        else v2 = sp;
    }
#pragma unroll
    for (int msk = 1; msk < 64; msk <<= 1) {
        v0 += __shfl_xor(v0, msk);
        v1 += __shfl_xor(v1, msk);
        v2 += __shfl_xor(v2, msk);
    }
    __shared__ float so[4][3];
    if (lane == 0) { so[wid][0] = v0; so[wid][1] = v1; so[wid][2] = v2; }
    __syncthreads();
    if (threadIdx.x == 0) {
        float* slot = ws + OPART + bid * 4;
        slot[0] = so[0][0] + so[1][0] + so[2][0] + so[3][0];
        slot[1] = so[0][1] + so[1][1] + so[2][1] + so[3][1];
        slot[2] = so[0][2] + so[1][2] + so[2][2] + so[3][2];
        slot[3] = 0.f;
    }
}

// Single 256-thread block reducer — STATIC indexing only (rule #20). Per-level loops
// fully unrolled; 240 slots/level -> one conditional float4 load per thread per level.
// (R13 exact version — measured best; the 1024-thread variant of R14 regressed.)
__global__ __launch_bounds__(256) void k_final(const float* __restrict__ ws,
                                               float* __restrict__ out) {
    const int tid = threadIdx.x;
    const int wid = tid >> 6, lane = tid & 63;

    // acc: [0..2]=lbox [3..5]=cls [6..8]=cnt [9..11]=xt [12..14]=softplus (const-indexed)
    float acc[15];
#pragma unroll
    for (int q = 0; q < 15; ++q) acc[q] = 0.f;

#pragma unroll
    for (int l = 0; l < 3; ++l) {
        if (tid < 240) {
            const float4 s = *(const float4*)(ws + TPART + (l * 240 + tid) * 4);
            acc[l] = s.x;       // lbox
            acc[3 + l] = s.y;   // cls
            acc[6 + l] = s.z;   // cnt
            acc[9 + l] = s.w;   // xt
        }
    }
    // obj softplus partials: 1331 slots, float4, 6 independent iterations
    for (int t = tid; t < NBLK; t += 256) {
        const float4 s = *(const float4*)(ws + OPART + t * 4);
        acc[12] += s.x;
        acc[13] += s.y;
        acc[14] += s.z;
    }

#pragma unroll
    for (int q = 0; q < 15; ++q)
#pragma unroll
        for (int msk = 32; msk; msk >>= 1) acc[q] += __shfl_xor(acc[q], msk);

    __shared__ float sf[4][15];
    if (lane == 0)
#pragma unroll
        for (int q = 0; q < 15; ++q) sf[wid][q] = acc[q];
    __syncthreads();

    if (tid == 0) {
        float lbox = 0.f, lobj = 0.f, lcls = 0.f;
        const float bal[3] = {4.0f, 1.0f, 0.4f};
        const float ncell[3] = {(float)CELL0, (float)CELL1, (float)CELL2};
#pragma unroll
        for (int l = 0; l < 3; ++l) {
            const float sbv = sf[0][l] + sf[1][l] + sf[2][l] + sf[3][l];
            const float scv = sf[0][3 + l] + sf[1][3 + l] + sf[2][3 + l] + sf[3][3 + l];
            const float snv = sf[0][6 + l] + sf[1][6 + l] + sf[2][6 + l] + sf[3][6 + l];
            const float sxt = sf[0][9 + l] + sf[1][9 + l] + sf[2][9 + l] + sf[3][9 + l];
            const float sov = sf[0][12 + l] + sf[1][12 + l] + sf[2][12 + l] + sf[3][12 + l];
            const float nv = fmaxf(snv, 1.0f);
            lbox += sbv / nv;
            lcls += scv / (nv * (float)NCLS);
            lobj += (sov - sxt) / ncell[l] * bal[l];  // bce(x,t) = softplus(x) - x*t
        }
        lbox *= 0.05f;
        lcls *= 0.5f;
        const float total = (lbox + lobj + lcls) * 32.0f;
        out[0] = total;
        out[1] = lbox;
        out[2] = lobj;
        out[3] = lcls;
    }
}

extern "C" void kernel_launch(void* const* d_in, const int* in_sizes, int n_in,
                              void* d_out, int out_size, void* d_ws, size_t ws_size,
                              hipStream_t stream) {
    const float* p0 = (const float*)d_in[0];
    const float* p1 = (const float*)d_in[1];
    const float* p2 = (const float*)d_in[2];
    const float* tgt = (const float*)d_in[3];
    float* ws = (float*)d_ws;
    float* out = (float*)d_out;

    k_all<<<NBLK, 256, 0, stream>>>(p0, p1, p2, tgt, ws);
    k_final<<<1, 256, 0, stream>>>(ws, out);
}